// Round 1
// baseline (126.157 us; speedup 1.0000x reference)
//
#include <hip/hip_runtime.h>
#include <cstdint>
#include <cstddef>

// Problem constants: B=8, C=64, H=W=32 -> N=8192 nodes, K=9 neighbors, OUT=64.
// Batches (from linspace truncation): k = [1024k,1024(k+1)) for k<=6,
// batch 7 = [7168,8190], batch 8 = {8191} (singleton -> mean = self).

// ---------------------------------------------------------------------------
// K1: transpose x (8,64,32,32) -> xf[8192][64], and sq[n] = sum_c xf[n][c]^2
// (sequential-c accumulation order to match K3's dot order -> self-dist == 0)
// ---------------------------------------------------------------------------
__global__ __launch_bounds__(256) void k_transpose_sq(const float* __restrict__ x,
                                                      float* __restrict__ xf,
                                                      float* __restrict__ sq) {
  __shared__ float tile[64][65];
  int blk = blockIdx.x;           // 128 blocks: 8 b x 16 hw-tiles
  int b = blk >> 4;
  int hw0 = (blk & 15) << 6;
  int t = threadIdx.x;
  int lane_hw = t & 63;
  int c_base = t >> 6;            // 0..3
#pragma unroll
  for (int i = 0; i < 16; ++i) {
    int c = c_base + (i << 2);
    tile[c][lane_hw] = x[((b * 64 + c) << 10) + hw0 + lane_hw];
  }
  __syncthreads();
  int c_out = t & 63;
  int hw_base = t >> 6;
#pragma unroll
  for (int i = 0; i < 16; ++i) {
    int hw = hw_base + (i << 2);
    xf[(size_t)(((b << 10) + hw0 + hw) << 6) + c_out] = tile[c_out][hw];
  }
  if (t < 64) {
    float s = 0.f;
#pragma unroll
    for (int c = 0; c < 64; ++c) { float v = tile[c][t]; s += v * v; }
    sq[(b << 10) + hw0 + t] = s;
  }
}

// ---------------------------------------------------------------------------
// K3: distance GEMM. D[i][jj] = sq[i] + sq[s(i)+jj] - 2*dot(xf[i], xf[s(i)+jj])
// for jj in [0,1024). s(i) = batch start (batches 7,8 merged: s=7168).
// 128x128 tile / block, 8x8 per thread, K=64 in 2 LDS passes of 32.
// ---------------------------------------------------------------------------
__global__ __launch_bounds__(256) void k_dist(const float* __restrict__ xf,
                                              const float* __restrict__ sq,
                                              float* __restrict__ D) {
  __shared__ float As[32][132];   // [k][m], pad->aligned b128 + conflict-free
  __shared__ float Bs[32][132];   // [k][n]
  int i0 = blockIdx.y << 7;       // 0..8064
  int jj0 = blockIdx.x << 7;      // 0..896
  int s = (i0 >= 7168) ? 7168 : (i0 & ~1023);
  int j0 = s + jj0;
  int t = threadIdx.x;
  int tx = t & 15, ty = t >> 4;

  float acc[8][8];
#pragma unroll
  for (int r = 0; r < 8; ++r)
#pragma unroll
    for (int c = 0; c < 8; ++c) acc[r][c] = 0.f;

  for (int pass = 0; pass < 2; ++pass) {
    __syncthreads();
#pragma unroll
    for (int i = 0; i < 4; ++i) {
      int lin = t + (i << 8);     // 0..1023 float4 units
      int m = lin >> 3;           // 0..127
      int k4 = lin & 7;           // 0..7
      const float4 va = *(const float4*)&xf[(size_t)((i0 + m) << 6) + (pass << 5) + (k4 << 2)];
      As[(k4 << 2) + 0][m] = va.x;
      As[(k4 << 2) + 1][m] = va.y;
      As[(k4 << 2) + 2][m] = va.z;
      As[(k4 << 2) + 3][m] = va.w;
      const float4 vb = *(const float4*)&xf[(size_t)((j0 + m) << 6) + (pass << 5) + (k4 << 2)];
      Bs[(k4 << 2) + 0][m] = vb.x;
      Bs[(k4 << 2) + 1][m] = vb.y;
      Bs[(k4 << 2) + 2][m] = vb.z;
      Bs[(k4 << 2) + 3][m] = vb.w;
    }
    __syncthreads();
#pragma unroll 4
    for (int k = 0; k < 32; ++k) {
      float4 a0 = *(const float4*)&As[k][ty << 2];
      float4 a1 = *(const float4*)&As[k][64 + (ty << 2)];
      float4 b0 = *(const float4*)&Bs[k][tx << 2];
      float4 b1 = *(const float4*)&Bs[k][64 + (tx << 2)];
      float av[8] = {a0.x, a0.y, a0.z, a0.w, a1.x, a1.y, a1.z, a1.w};
      float bv[8] = {b0.x, b0.y, b0.z, b0.w, b1.x, b1.y, b1.z, b1.w};
#pragma unroll
      for (int r = 0; r < 8; ++r)
#pragma unroll
        for (int c = 0; c < 8; ++c)
          acc[r][c] += av[r] * bv[c];
    }
  }

  int mrow[8], ncol[8];
#pragma unroll
  for (int r = 0; r < 4; ++r) { mrow[r] = (ty << 2) + r; mrow[4 + r] = 64 + (ty << 2) + r; }
#pragma unroll
  for (int c = 0; c < 4; ++c) { ncol[c] = (tx << 2) + c; ncol[4 + c] = 64 + (tx << 2) + c; }
  float sqi[8], sqj[8];
#pragma unroll
  for (int r = 0; r < 8; ++r) sqi[r] = sq[i0 + mrow[r]];
#pragma unroll
  for (int c = 0; c < 8; ++c) sqj[c] = sq[j0 + ncol[c]];
#pragma unroll
  for (int r = 0; r < 8; ++r) {
    int row = i0 + mrow[r];
    float4 o0, o1;
    o0.x = sqi[r] + sqj[0] - 2.f * acc[r][0];
    o0.y = sqi[r] + sqj[1] - 2.f * acc[r][1];
    o0.z = sqi[r] + sqj[2] - 2.f * acc[r][2];
    o0.w = sqi[r] + sqj[3] - 2.f * acc[r][3];
    o1.x = sqi[r] + sqj[4] - 2.f * acc[r][4];
    o1.y = sqi[r] + sqj[5] - 2.f * acc[r][5];
    o1.z = sqi[r] + sqj[6] - 2.f * acc[r][6];
    o1.w = sqi[r] + sqj[7] - 2.f * acc[r][7];
    *(float4*)&D[((size_t)row << 10) + jj0 + (tx << 2)] = o0;
    *(float4*)&D[((size_t)row << 10) + jj0 + 64 + (tx << 2)] = o1;
  }
}

// ---------------------------------------------------------------------------
// K4: exact top-9 per row (one wave per row). Key = (orderable-dist << 32)|jj
// -> min picks smallest dist, ties -> smallest index (matches lax.top_k).
// ---------------------------------------------------------------------------
__global__ __launch_bounds__(256) void k_select(const float* __restrict__ D,
                                                int* __restrict__ idxO) {
  int t = threadIdx.x;
  int lane = t & 63;
  int i = (blockIdx.x << 2) + (t >> 6);
  if (i == 8191) {                 // singleton batch: neighbor = self
    if (lane == 0) idxO[i * 9] = 8191;
    return;
  }
  int s = (i >= 7168) ? 7168 : (i & ~1023);
  bool mlast = (i >= 7168);        // rows of batch 7 must exclude j=8191
  const float* drow = D + ((size_t)i << 10);
  unsigned long long cand[16];
#pragma unroll
  for (int q = 0; q < 16; ++q) {
    int jj = lane + (q << 6);
    float d = drow[jj];
    unsigned u = __float_as_uint(d);
    u = (u & 0x80000000u) ? ~u : (u | 0x80000000u);
    unsigned long long key = ((unsigned long long)u << 32) | (unsigned)jj;
    if (mlast && jj == 1023) key = ~0ull;
    cand[q] = key;
  }
#pragma unroll
  for (int kk = 0; kk < 9; ++kk) {
    unsigned long long m = cand[0];
#pragma unroll
    for (int q = 1; q < 16; ++q) m = (cand[q] < m) ? cand[q] : m;
#pragma unroll
    for (int off = 32; off > 0; off >>= 1) {
      unsigned hi = __shfl_xor((unsigned)(m >> 32), off, 64);
      unsigned lo = __shfl_xor((unsigned)(m & 0xffffffffu), off, 64);
      unsigned long long o = ((unsigned long long)hi << 32) | lo;
      m = (o < m) ? o : m;
    }
    if (lane == 0) idxO[i * 9 + kk] = s + (int)(m & 0xffffffffu);
#pragma unroll
    for (int q = 0; q < 16; ++q) if (cand[q] == m) cand[q] = ~0ull;
  }
}

// ---------------------------------------------------------------------------
// K5: mean of neighbors + out = mean@Wl^T + bl + xf@Wr^T.
// Lane o holds W rows (128 VGPRs); mean/xf broadcast via v_readlane -> SGPR
// FMA operands; no LDS in the hot loop.
// ---------------------------------------------------------------------------
__global__ __launch_bounds__(256) void k_out(const float* __restrict__ xf,
                                             const int* __restrict__ idxO,
                                             const float* __restrict__ Wl,
                                             const float* __restrict__ bl,
                                             const float* __restrict__ Wr,
                                             float* __restrict__ out) {
  __shared__ float WsL[64][65];
  __shared__ float WsR[64][65];
  int t = threadIdx.x;
#pragma unroll
  for (int i = 0; i < 16; ++i) {
    int lin = t + (i << 8);
    WsL[lin >> 6][lin & 63] = Wl[lin];
    WsR[lin >> 6][lin & 63] = Wr[lin];
  }
  __syncthreads();
  int lane = t & 63;
  float wl[64], wr[64];
#pragma unroll
  for (int c = 0; c < 64; ++c) { wl[c] = WsL[lane][c]; wr[c] = WsR[lane][c]; }
  float bias = bl[lane];
  int wave = t >> 6;
  int n0 = (blockIdx.x << 4) + (wave << 2);   // 4 nodes per wave
  for (int nn = 0; nn < 4; ++nn) {
    int n = n0 + nn;
    int cnt = (n == 8191) ? 1 : 9;            // wave-uniform
    float msum = 0.f;
    for (int k = 0; k < cnt; ++k) {
      int j = idxO[n * 9 + k];                // uniform -> s_load
      msum += xf[((size_t)j << 6) + lane];    // coalesced gather
    }
    float mean = msum / (float)cnt;           // lane c = feature c
    float xr = xf[((size_t)n << 6) + lane];
    float acc = bias;
#pragma unroll
    for (int c = 0; c < 64; ++c) {
      float mc = __int_as_float(__builtin_amdgcn_readlane(__float_as_int(mean), c));
      float xc = __int_as_float(__builtin_amdgcn_readlane(__float_as_int(xr), c));
      acc += mc * wl[c];
      acc += xc * wr[c];
    }
    out[((size_t)n << 6) + lane] = acc;
  }
}

// ---------------------------------------------------------------------------
extern "C" void kernel_launch(void* const* d_in, const int* in_sizes, int n_in,
                              void* d_out, int out_size, void* d_ws, size_t ws_size,
                              hipStream_t stream) {
  const float* x  = (const float*)d_in[0];   // (8,64,32,32)
  const float* Wl = (const float*)d_in[1];   // (64,64)
  const float* bl = (const float*)d_in[2];   // (64,)
  const float* Wr = (const float*)d_in[3];   // (64,64)
  float* out = (float*)d_out;                // (8192,64)

  char* ws = (char*)d_ws;
  float* xf  = (float*)(ws);                                   // 2,097,152 B
  float* sq  = (float*)(ws + 2097152);                         //    32,768 B
  int*   idx = (int*)  (ws + 2097152 + 32768);                 //   294,912 B
  float* D   = (float*)(ws + 2097152 + 32768 + 294912);        // 33,554,432 B
  // total ws use: 35,979,264 B

  k_transpose_sq<<<128, 256, 0, stream>>>(x, xf, sq);
  k_dist<<<dim3(8, 64), 256, 0, stream>>>(xf, sq, D);
  k_select<<<2048, 256, 0, stream>>>(D, idx);
  k_out<<<512, 256, 0, stream>>>(xf, idx, Wl, bl, Wr, out);
}